// Round 11
// baseline (149.971 us; speedup 1.0000x reference)
//
#include <hip/hip_runtime.h>
#include <hip/hip_cooperative_groups.h>

namespace cg = cooperative_groups;

#define HEADS 8
#define CH    64      // per-head dim == x channel dim
#define HW    4096
#define MTOK  256     // z tokens
#define DIMZ  256     // z feature dim
#define INNER 512     // heads*CH
#define LROWS 512     // HW/8 distinct query rows per head

typedef __attribute__((ext_vector_type(8))) __bf16 bf16x8;
typedef __attribute__((ext_vector_type(4))) float  f32x4;

// round-to-nearest-even f32 -> bf16 bits
__device__ __forceinline__ unsigned f2bf(float f) {
  unsigned u = __float_as_uint(f);
  return (u + 0x7fffu + ((u >> 16) & 1u)) >> 16;
}

__device__ __forceinline__ bf16x8 ld_bf8(const unsigned short* p) {
  uint4 v = *(const uint4*)p;
  return __builtin_bit_cast(bf16x8, v);
}

// 8 consecutive f32 -> bf16x8
__device__ __forceinline__ bf16x8 cvt8(const float* p) {
  float4 f0 = *(const float4*)p;
  float4 f1 = *(const float4*)(p + 4);
  uint4 u;
  u.x = f2bf(f0.x) | (f2bf(f0.y) << 16);
  u.y = f2bf(f0.z) | (f2bf(f0.w) << 16);
  u.z = f2bf(f1.x) | (f2bf(f1.y) << 16);
  u.w = f2bf(f1.z) | (f2bf(f1.w) << 16);
  return __builtin_bit_cast(bf16x8, u);
}

// ---------------------------------------------------------------------------
// ONE cooperative kernel: Phase 0 = kv_gen (R10 body, 2 virtual 256-thread
// halves per block) + Wo direct transpose; grid.sync(); Phase A = per-wave
// attention; Phase B = proj + residual (R10 attnproj verbatim, + x issue-early).
// 256 blocks x 512 threads, 80 KB LDS.
// ---------------------------------------------------------------------------
__global__ __launch_bounds__(512) void fused_all(
    const float* __restrict__ x, const float* __restrict__ z,
    const float* __restrict__ Wk, const float* __restrict__ bk,
    const float* __restrict__ Wv, const float* __restrict__ bv,
    const float* __restrict__ Wo, const float* __restrict__ bo,
    unsigned short* __restrict__ klin, unsigned short* __restrict__ vt,
    unsigned short* __restrict__ WoT, float* __restrict__ y) {
  __shared__ __align__(16) char lds[81920];
  const int t = threadIdx.x;
  const int bid = blockIdx.x;

  // ================= Phase 0: KV generation (2 halves/block) ==============
  {
    const int half = t >> 8, ht = t & 255;
    const int vb = bid * 2 + half;             // 512 virtual kv blocks
    const int mb = vb >> 4, bn = vb & 15;
    const bool isK = bn < 8;
    const int nb = bn & 7;
    const float* __restrict__ W    = isK ? Wk : Wv;
    const float* __restrict__ bias = isK ? bk : bv;
    const int lane = ht & 63, wid4 = ht >> 6;
    const int c = lane & 15, g = lane >> 4;
    const int m0 = mb * 64 + (wid4 >> 1) * 32;
    const int n0 = nb * 64 + (wid4 & 1) * 32;
    const int nloc = (wid4 & 1) * 32;
    const int skk = ht >> 3, snn = (ht & 7) * 8;   // staging coords
    // Tw[2][64][40] ushort per half = 10240 B
    unsigned short* Tw = (unsigned short*)(lds + half * 10240);
    #define TW(buf, n, k) Tw[((buf) * 64 + (n)) * 40 + (k)]

    f32x4 acc[2][2];
#pragma unroll
    for (int i = 0; i < 2; ++i)
#pragma unroll
      for (int j = 0; j < 2; ++j) acc[i][j] = (f32x4)0.f;

    // stage step 0
    {
      const float* wp = W + (size_t)skk * INNER + nb * 64 + snn;
      float4 w0 = *(const float4*)wp;
      float4 w1 = *(const float4*)(wp + 4);
      TW(0, snn + 0, skk) = (unsigned short)f2bf(w0.x);
      TW(0, snn + 1, skk) = (unsigned short)f2bf(w0.y);
      TW(0, snn + 2, skk) = (unsigned short)f2bf(w0.z);
      TW(0, snn + 3, skk) = (unsigned short)f2bf(w0.w);
      TW(0, snn + 4, skk) = (unsigned short)f2bf(w1.x);
      TW(0, snn + 5, skk) = (unsigned short)f2bf(w1.y);
      TW(0, snn + 6, skk) = (unsigned short)f2bf(w1.z);
      TW(0, snn + 7, skk) = (unsigned short)f2bf(w1.w);
    }
    __syncthreads();

#pragma unroll
    for (int s = 0; s < 8; ++s) {
      const int k0 = s * 32;
      if (s < 7) {   // stage step s+1 into the other buffer (overlaps MFMA)
        const int nb2 = (s + 1) & 1;
        const float* wp = W + (size_t)(k0 + 32 + skk) * INNER + nb * 64 + snn;
        float4 w0 = *(const float4*)wp;
        float4 w1 = *(const float4*)(wp + 4);
        TW(nb2, snn + 0, skk) = (unsigned short)f2bf(w0.x);
        TW(nb2, snn + 1, skk) = (unsigned short)f2bf(w0.y);
        TW(nb2, snn + 2, skk) = (unsigned short)f2bf(w0.z);
        TW(nb2, snn + 3, skk) = (unsigned short)f2bf(w0.w);
        TW(nb2, snn + 4, skk) = (unsigned short)f2bf(w1.x);
        TW(nb2, snn + 5, skk) = (unsigned short)f2bf(w1.y);
        TW(nb2, snn + 6, skk) = (unsigned short)f2bf(w1.z);
        TW(nb2, snn + 7, skk) = (unsigned short)f2bf(w1.w);
      }
      const int cbuf = s & 1;
      bf16x8 a0 = cvt8(z + (size_t)(m0 + c) * DIMZ + k0 + 8 * g);
      bf16x8 a1 = cvt8(z + (size_t)(m0 + 16 + c) * DIMZ + k0 + 8 * g);
      bf16x8 b0 = *(const bf16x8*)&TW(cbuf, nloc + c, 8 * g);
      bf16x8 b1 = *(const bf16x8*)&TW(cbuf, nloc + 16 + c, 8 * g);
      if (isK) {   // D[n][m]
        acc[0][0] = __builtin_amdgcn_mfma_f32_16x16x32_bf16(b0, a0, acc[0][0], 0, 0, 0);
        acc[0][1] = __builtin_amdgcn_mfma_f32_16x16x32_bf16(b1, a0, acc[0][1], 0, 0, 0);
        acc[1][0] = __builtin_amdgcn_mfma_f32_16x16x32_bf16(b0, a1, acc[1][0], 0, 0, 0);
        acc[1][1] = __builtin_amdgcn_mfma_f32_16x16x32_bf16(b1, a1, acc[1][1], 0, 0, 0);
      } else {     // D[m][n]
        acc[0][0] = __builtin_amdgcn_mfma_f32_16x16x32_bf16(a0, b0, acc[0][0], 0, 0, 0);
        acc[0][1] = __builtin_amdgcn_mfma_f32_16x16x32_bf16(a0, b1, acc[0][1], 0, 0, 0);
        acc[1][0] = __builtin_amdgcn_mfma_f32_16x16x32_bf16(a1, b0, acc[1][0], 0, 0, 0);
        acc[1][1] = __builtin_amdgcn_mfma_f32_16x16x32_bf16(a1, b1, acc[1][1], 0, 0, 0);
      }
      __syncthreads();
    }
    #undef TW

    if (isK) {
      // rows n = n0+nt*16+4g+r, col m = m0+mt*16+c
#pragma unroll
      for (int mt = 0; mt < 2; ++mt)
#pragma unroll
        for (int nt = 0; nt < 2; ++nt) {
          const int m = m0 + mt * 16 + c;
          const int n = n0 + nt * 16 + 4 * g;
          float4 b4 = *(const float4*)(bias + n);
          uint2 w;
          w.x = f2bf(acc[mt][nt][0] + b4.x) | (f2bf(acc[mt][nt][1] + b4.y) << 16);
          w.y = f2bf(acc[mt][nt][2] + b4.z) | (f2bf(acc[mt][nt][3] + b4.w) << 16);
          *(uint2*)(klin + (size_t)m * INNER + n) = w;
        }
    } else {
      // rows m = m0+mt*16+4g+r (tokens), col n = n0+nt*16+c
#pragma unroll
      for (int mt = 0; mt < 2; ++mt)
#pragma unroll
        for (int nt = 0; nt < 2; ++nt) {
          const int n = n0 + nt * 16 + c;
          const float bn1 = bias[n];
          const int m = m0 + mt * 16 + 4 * g;
          const int bb = m >> 8;
          const int mtk = m & 255;
          const int h = mtk >> 5, t0 = mtk & 31;
          const int cc2 = n & 63, cb2 = n >> 6;
          uint2 w;
          w.x = f2bf(acc[mt][nt][0] + bn1) | (f2bf(acc[mt][nt][1] + bn1) << 16);
          w.y = f2bf(acc[mt][nt][2] + bn1) | (f2bf(acc[mt][nt][3] + bn1) << 16);
          *(uint2*)(vt + ((size_t)((bb * HEADS + h) * CH + cc2)) * MTOK + cb2 * 32 + t0) = w;
        }
    }
  }

  // ---- Wo (512x64) -> WoT (64x512), direct strided copy, no barriers ----
  if (bid >= 252) {
    const int idx0 = (bid - 252) * 512 + t;
#pragma unroll
    for (int it = 0; it < 4; ++it) {
      int gidx = idx0 + it * 2048;       // 0..8191
      int n = gidx >> 7, k0 = (gidx & 127) * 4;
      uint2 w;
      w.x = f2bf(Wo[(size_t)k0 * CH + n])       | (f2bf(Wo[(size_t)(k0 + 1) * CH + n]) << 16);
      w.y = f2bf(Wo[(size_t)(k0 + 2) * CH + n]) | (f2bf(Wo[(size_t)(k0 + 3) * CH + n]) << 16);
      *(uint2*)(WoT + (size_t)n * INNER + k0) = w;
    }
  }

  __threadfence();
  cg::this_grid().sync();

  // ================= Phase A: 16-query attention, head = wave ==============
  char* Osh = lds + 65536;
  float* Sp = (float*)lds;                    // [8][16][68] overlaps P region
  const int lane = t & 63, wid = t >> 6;
  const int c = lane & 15, g = lane >> 4;
  const int qc = bid & 31, b = bid >> 5;
  const int hh = wid;
  const int qbase = qc * 16;
  char* Pb = lds + wid * 8192;

  {
    const float* xs = x + (size_t)b * (HW * CH) + (size_t)hh * (LROWS * CH);
    const unsigned short* Kg = klin + ((size_t)b * MTOK + hh * 32) * INNER;
    const unsigned short* Vg = vt + (size_t)(b * HEADS + hh) * (CH * MTOK);

    // Q fragment (B-operand); scale (1/8)*log2e folded in
    const float qs = 0.125f * 1.44269504089f;
    bf16x8 qfr[2];
#pragma unroll
    for (int ks = 0; ks < 2; ++ks) {
      const float* qp = xs + (size_t)(qbase + c) * CH + 32 * ks + 8 * g;
      float4 f0 = *(const float4*)qp;
      float4 f1 = *(const float4*)(qp + 4);
      uint4 u;
      u.x = f2bf(f0.x * qs) | (f2bf(f0.y * qs) << 16);
      u.y = f2bf(f0.z * qs) | (f2bf(f0.w * qs) << 16);
      u.z = f2bf(f1.x * qs) | (f2bf(f1.y * qs) << 16);
      u.w = f2bf(f1.z * qs) | (f2bf(f1.w * qs) << 16);
      qfr[ks] = __builtin_bit_cast(bf16x8, u);
    }

    // S'^T = K . Q^T : acc[kf]; key' = 16*kf + (4g+r), col q = c
    f32x4 acc[16];
#pragma unroll
    for (int kf = 0; kf < 16; ++kf) acc[kf] = (f32x4)0.f;
#pragma unroll
    for (int kf = 0; kf < 16; ++kf) {
      const unsigned short* kp =
          Kg + (size_t)((kf & 1) * 16 + c) * INNER + (kf >> 1) * 64 + 8 * g;
      bf16x8 a0 = ld_bf8(kp);
      bf16x8 a1 = ld_bf8(kp + 32);
      acc[kf] = __builtin_amdgcn_mfma_f32_16x16x32_bf16(a0, qfr[0], acc[kf], 0, 0, 0);
      acc[kf] = __builtin_amdgcn_mfma_f32_16x16x32_bf16(a1, qfr[1], acc[kf], 0, 0, 0);
    }

    // V issue-early prefetch (first half): hides L2 latency under softmax
    uint4 vpre[4][4];
#pragma unroll
    for (int ks = 0; ks < 4; ++ks)
#pragma unroll
      for (int cf = 0; cf < 4; ++cf)
        vpre[ks][cf] =
            *(const uint4*)(Vg + (size_t)(16 * cf + c) * MTOK + 32 * ks + 8 * g);

    // softmax in log2 domain (normalization deferred) + P write
    float m = acc[0][0];
#pragma unroll
    for (int kf = 0; kf < 16; ++kf)
      m = fmaxf(m, fmaxf(fmaxf(acc[kf][0], acc[kf][1]),
                         fmaxf(acc[kf][2], acc[kf][3])));
    m = fmaxf(m, __shfl_xor(m, 16));
    m = fmaxf(m, __shfl_xor(m, 32));
    float sum = 0.f;
    const int rowb = c * 512;               // 256 ushort per P row
#pragma unroll
    for (int kf = 0; kf < 16; ++kf) {
      float e0 = exp2f(acc[kf][0] - m);
      float e1 = exp2f(acc[kf][1] - m);
      float e2 = exp2f(acc[kf][2] - m);
      float e3 = exp2f(acc[kf][3] - m);
      sum += (e0 + e1) + (e2 + e3);
      uint2 w;
      w.x = f2bf(e0) | (f2bf(e1) << 16);
      w.y = f2bf(e2) | (f2bf(e3) << 16);
      *(uint2*)(Pb + ((rowb + (16 * kf + 4 * g) * 2) ^ ((c & 7) << 4))) = w;
    }
    sum += __shfl_xor(sum, 16);
    sum += __shfl_xor(sum, 32);
    const float inv = 1.f / sum;
    asm volatile("" ::: "memory");  // keep P writes before P reads

    // O^T = V^T . P : o[cf], rows=channels, cols=queries
    f32x4 o[4];
#pragma unroll
    for (int cf = 0; cf < 4; ++cf) o[cf] = (f32x4)0.f;
#pragma unroll
    for (int ks = 0; ks < 8; ++ks) {
      bf16x8 p = __builtin_bit_cast(bf16x8,
          *(const uint4*)(Pb + ((c * 512 + (32 * ks + 8 * g) * 2) ^ ((c & 7) << 4))));
#pragma unroll
      for (int cf = 0; cf < 4; ++cf) {
        bf16x8 a = (ks < 4)
            ? __builtin_bit_cast(bf16x8, vpre[ks][cf])
            : ld_bf8(Vg + (size_t)(16 * cf + c) * MTOK + 32 * ks + 8 * g);
        o[cf] = __builtin_amdgcn_mfma_f32_16x16x32_bf16(a, p, o[cf], 0, 0, 0);
      }
    }

    // normalize + store bf16 to Osh[q=c][col = hh*64 + 16cf + 4g + r]
#pragma unroll
    for (int cf = 0; cf < 4; ++cf) {
      f32x4 r = o[cf] * inv;
      uint2 w;
      w.x = f2bf(r[0]) | (f2bf(r[1]) << 16);
      w.y = f2bf(r[2]) | (f2bf(r[3]) << 16);
      int off = (c * 1024 + (hh * 64 + 16 * cf + 4 * g) * 2) ^ ((c & 7) << 4);
      *(uint2*)(Osh + off) = w;
    }
  }

  // x residual rows: issue-early (HBM latency hides under Phase B MFMA)
  const int ei = t >> 5, ejj = t & 31;
  const int ej0 = (ejj & 15) * 4, erh = ejj >> 4;
  const int eL = qbase + ei;
  const float* xr = x + (size_t)b * (HW * CH) + (size_t)eL * 8 * CH + ej0;
  float4 xv[4];
#pragma unroll
  for (int r = 0; r < 4; ++r) xv[r] = *(const float4*)(xr + (erh * 4 + r) * CH);

  __syncthreads();   // P dead from here; its region becomes Sp

  // ================= Phase B: proj + residual ==============
  {
    const int kw = wid * 64;
    f32x4 acc[4];
#pragma unroll
    for (int nt = 0; nt < 4; ++nt) acc[nt] = (f32x4)0.f;
#pragma unroll
    for (int s = 0; s < 2; ++s) {
      const int k0 = kw + s * 32;
      bf16x8 bfr = __builtin_bit_cast(bf16x8,
          *(const uint4*)(Osh + ((c * 1024 + (k0 + 8 * g) * 2) ^ ((c & 7) << 4))));
#pragma unroll
      for (int nt = 0; nt < 4; ++nt) {
        bf16x8 afr = ld_bf8(WoT + (size_t)(nt * 16 + c) * INNER + k0 + 8 * g);
        acc[nt] = __builtin_amdgcn_mfma_f32_16x16x32_bf16(afr, bfr, acc[nt], 0, 0, 0);
      }
    }
#pragma unroll
    for (int nt = 0; nt < 4; ++nt)
      *(f32x4*)&Sp[(wid * 16 + c) * 68 + nt * 16 + 4 * g] = acc[nt];
  }
  __syncthreads();

  // epilogue over all 512 threads
  float4 b4 = *(const float4*)(bo + ej0);
  float4 o4 = b4;
#pragma unroll
  for (int w = 0; w < 8; ++w) {
    float4 s = *(const float4*)&Sp[(w * 16 + ei) * 68 + ej0];
    o4.x += s.x; o4.y += s.y; o4.z += s.z; o4.w += s.w;
  }
  float* yr = y + (size_t)b * (HW * CH) + (size_t)eL * 8 * CH + ej0;
#pragma unroll
  for (int r = 0; r < 4; ++r) {
    float4 ov = make_float4(o4.x + xv[r].x, o4.y + xv[r].y,
                            o4.z + xv[r].z, o4.w + xv[r].w);
    *(float4*)(yr + (erh * 4 + r) * CH) = ov;
  }
}

extern "C" void kernel_launch(void* const* d_in, const int* in_sizes, int n_in,
                              void* d_out, int out_size, void* d_ws, size_t ws_size,
                              hipStream_t stream) {
  const float* x  = (const float*)d_in[0];
  const float* z  = (const float*)d_in[1];
  const float* Wk = (const float*)d_in[2];
  const float* bk = (const float*)d_in[3];
  const float* Wv = (const float*)d_in[4];
  const float* bv = (const float*)d_in[5];
  const float* Wo = (const float*)d_in[6];
  const float* bo = (const float*)d_in[7];
  float* y = (float*)d_out;

  // ws (ushort units): klin 1M | vt 1M | WoT 32K  (~4.3 MB)
  unsigned short* klin = (unsigned short*)d_ws;
  unsigned short* vt   = klin + (size_t)2048 * INNER;
  unsigned short* WoT  = vt   + (size_t)2048 * INNER;

  void* args[12] = {&x, &z, &Wk, &bk, &Wv, &bv, &Wo, &bo,
                    &klin, &vt, &WoT, &y};
  hipLaunchCooperativeKernel((const void*)fused_all, dim3(256), dim3(512),
                             args, 0, stream);
}

// Round 12
// 40.893 us; speedup vs baseline: 3.6674x; 3.6674x over previous
//
#include <hip/hip_runtime.h>

#define HEADS 8
#define CH    64      // per-head dim == x channel dim
#define HW    4096
#define MTOK  256     // z tokens
#define DIMZ  256     // z feature dim
#define INNER 512     // heads*CH
#define LROWS 512     // HW/8 distinct query rows per head

typedef __attribute__((ext_vector_type(8))) __bf16 bf16x8;
typedef __attribute__((ext_vector_type(4))) float  f32x4;

// round-to-nearest-even f32 -> bf16 bits
__device__ __forceinline__ unsigned f2bf(float f) {
  unsigned u = __float_as_uint(f);
  return (u + 0x7fffu + ((u >> 16) & 1u)) >> 16;
}

__device__ __forceinline__ bf16x8 ld_bf8(const unsigned short* p) {
  uint4 v = *(const uint4*)p;
  return __builtin_bit_cast(bf16x8, v);
}

// 8 consecutive f32 -> bf16x8
__device__ __forceinline__ bf16x8 cvt8(const float* p) {
  float4 f0 = *(const float4*)p;
  float4 f1 = *(const float4*)(p + 4);
  uint4 u;
  u.x = f2bf(f0.x) | (f2bf(f0.y) << 16);
  u.y = f2bf(f0.z) | (f2bf(f0.w) << 16);
  u.z = f2bf(f1.x) | (f2bf(f1.y) << 16);
  u.w = f2bf(f1.z) | (f2bf(f1.w) << 16);
  return __builtin_bit_cast(bf16x8, u);
}

// ---------------------------------------------------------------------------
// Kernel 1 (kv_gen): klin = bf16(z@Wk + bk) row-major (2048x512);
//   vt = bf16(z@Wv + bv) in [b][h][c][key'], key' = cb*32+t  (R5-validated).
// W^T fragments from a DOUBLE-BUFFERED per-k-step LDS transpose tile
// (one barrier per k-step; staging s+1 overlaps MFMA of s).
// Grid (32, 17): y 0..7 = K col-blocks, 8..15 = V col-blocks,
//                y==16 & x<8 = Wo -> WoT transpose.
// ---------------------------------------------------------------------------
__global__ __launch_bounds__(256) void kv_gen(
    const float* __restrict__ z,
    const float* __restrict__ Wk, const float* __restrict__ bk,
    const float* __restrict__ Wv, const float* __restrict__ bv,
    const float* __restrict__ Wo,
    unsigned short* __restrict__ klin, unsigned short* __restrict__ vt,
    unsigned short* __restrict__ WoT) {
  __shared__ unsigned short Tw[2][64][40];   // W^T tiles: [n][k], 80B rows
  __shared__ float Tf[64][65];               // Wo transpose tile
  const int t = threadIdx.x;
  const int bn = blockIdx.y;

  if (bn == 16) {   // ---- Wo (512x64) -> WoT (64x512), 8 blocks ----
    if (blockIdx.x >= 8) return;
    const int k0 = blockIdx.x * 64;
    const int rr = t >> 6, cc = t & 63;
#pragma unroll
    for (int it = 0; it < 16; ++it) {
      int r = it * 4 + rr;
      Tf[r][cc] = Wo[(size_t)(k0 + r) * CH + cc];
    }
    __syncthreads();
    const int nr = t >> 5, kp = t & 31;
#pragma unroll
    for (int it = 0; it < 8; ++it) {
      int n = it * 8 + nr;
      unsigned w = f2bf(Tf[kp * 2][n]) | (f2bf(Tf[kp * 2 + 1][n]) << 16);
      *(unsigned*)(WoT + (size_t)n * INNER + k0 + kp * 2) = w;
    }
    return;
  }

  const int lane = t & 63, wid = t >> 6;
  const int c = lane & 15, g = lane >> 4;
  const int mb = blockIdx.x;                 // 0..31 over 2048 token rows
  const bool isK = bn < 8;
  const int nb = bn & 7;
  const float* __restrict__ W    = isK ? Wk : Wv;
  const float* __restrict__ bias = isK ? bk : bv;
  const int m0 = mb * 64 + (wid >> 1) * 32;
  const int n0 = nb * 64 + (wid & 1) * 32;
  const int nloc = (wid & 1) * 32;
  const int skk = t >> 3, snn = (t & 7) * 8;   // staging coords

  f32x4 acc[2][2];
#pragma unroll
  for (int i = 0; i < 2; ++i)
#pragma unroll
    for (int j = 0; j < 2; ++j) acc[i][j] = (f32x4)0.f;

  // stage step 0
  {
    const float* wp = W + (size_t)skk * INNER + nb * 64 + snn;
    float4 w0 = *(const float4*)wp;
    float4 w1 = *(const float4*)(wp + 4);
    Tw[0][snn + 0][skk] = (unsigned short)f2bf(w0.x);
    Tw[0][snn + 1][skk] = (unsigned short)f2bf(w0.y);
    Tw[0][snn + 2][skk] = (unsigned short)f2bf(w0.z);
    Tw[0][snn + 3][skk] = (unsigned short)f2bf(w0.w);
    Tw[0][snn + 4][skk] = (unsigned short)f2bf(w1.x);
    Tw[0][snn + 5][skk] = (unsigned short)f2bf(w1.y);
    Tw[0][snn + 6][skk] = (unsigned short)f2bf(w1.z);
    Tw[0][snn + 7][skk] = (unsigned short)f2bf(w1.w);
  }
  __syncthreads();

#pragma unroll
  for (int s = 0; s < 8; ++s) {
    const int k0 = s * 32;
    if (s < 7) {   // stage step s+1 into the other buffer (overlaps MFMA)
      const int nb2 = (s + 1) & 1;
      const float* wp = W + (size_t)(k0 + 32 + skk) * INNER + nb * 64 + snn;
      float4 w0 = *(const float4*)wp;
      float4 w1 = *(const float4*)(wp + 4);
      Tw[nb2][snn + 0][skk] = (unsigned short)f2bf(w0.x);
      Tw[nb2][snn + 1][skk] = (unsigned short)f2bf(w0.y);
      Tw[nb2][snn + 2][skk] = (unsigned short)f2bf(w0.z);
      Tw[nb2][snn + 3][skk] = (unsigned short)f2bf(w0.w);
      Tw[nb2][snn + 4][skk] = (unsigned short)f2bf(w1.x);
      Tw[nb2][snn + 5][skk] = (unsigned short)f2bf(w1.y);
      Tw[nb2][snn + 6][skk] = (unsigned short)f2bf(w1.z);
      Tw[nb2][snn + 7][skk] = (unsigned short)f2bf(w1.w);
    }
    const int cb = s & 1;
    bf16x8 a0 = cvt8(z + (size_t)(m0 + c) * DIMZ + k0 + 8 * g);
    bf16x8 a1 = cvt8(z + (size_t)(m0 + 16 + c) * DIMZ + k0 + 8 * g);
    bf16x8 b0 = *(const bf16x8*)&Tw[cb][nloc + c][8 * g];
    bf16x8 b1 = *(const bf16x8*)&Tw[cb][nloc + 16 + c][8 * g];
    if (isK) {   // D[n][m]
      acc[0][0] = __builtin_amdgcn_mfma_f32_16x16x32_bf16(b0, a0, acc[0][0], 0, 0, 0);
      acc[0][1] = __builtin_amdgcn_mfma_f32_16x16x32_bf16(b1, a0, acc[0][1], 0, 0, 0);
      acc[1][0] = __builtin_amdgcn_mfma_f32_16x16x32_bf16(b0, a1, acc[1][0], 0, 0, 0);
      acc[1][1] = __builtin_amdgcn_mfma_f32_16x16x32_bf16(b1, a1, acc[1][1], 0, 0, 0);
    } else {     // D[m][n]
      acc[0][0] = __builtin_amdgcn_mfma_f32_16x16x32_bf16(a0, b0, acc[0][0], 0, 0, 0);
      acc[0][1] = __builtin_amdgcn_mfma_f32_16x16x32_bf16(a0, b1, acc[0][1], 0, 0, 0);
      acc[1][0] = __builtin_amdgcn_mfma_f32_16x16x32_bf16(a1, b0, acc[1][0], 0, 0, 0);
      acc[1][1] = __builtin_amdgcn_mfma_f32_16x16x32_bf16(a1, b1, acc[1][1], 0, 0, 0);
    }
    __syncthreads();
  }

  if (isK) {
    // rows n = n0+nt*16+4g+r, col m = m0+mt*16+c
#pragma unroll
    for (int mt = 0; mt < 2; ++mt)
#pragma unroll
      for (int nt = 0; nt < 2; ++nt) {
        const int m = m0 + mt * 16 + c;
        const int n = n0 + nt * 16 + 4 * g;
        float4 b4 = *(const float4*)(bias + n);
        uint2 w;
        w.x = f2bf(acc[mt][nt][0] + b4.x) | (f2bf(acc[mt][nt][1] + b4.y) << 16);
        w.y = f2bf(acc[mt][nt][2] + b4.z) | (f2bf(acc[mt][nt][3] + b4.w) << 16);
        *(uint2*)(klin + (size_t)m * INNER + n) = w;
      }
  } else {
    // rows m = m0+mt*16+4g+r (tokens), col n = n0+nt*16+c
#pragma unroll
    for (int mt = 0; mt < 2; ++mt)
#pragma unroll
      for (int nt = 0; nt < 2; ++nt) {
        const int n = n0 + nt * 16 + c;
        const float bn1 = bias[n];
        const int m = m0 + mt * 16 + 4 * g;
        const int bb = m >> 8;
        const int mtk = m & 255;
        const int h = mtk >> 5, t0 = mtk & 31;
        const int cc2 = n & 63, cb2 = n >> 6;
        uint2 w;
        w.x = f2bf(acc[mt][nt][0] + bn1) | (f2bf(acc[mt][nt][1] + bn1) << 16);
        w.y = f2bf(acc[mt][nt][2] + bn1) | (f2bf(acc[mt][nt][3] + bn1) << 16);
        *(uint2*)(vt + ((size_t)((bb * HEADS + h) * CH + cc2)) * MTOK + cb2 * 32 + t0) = w;
      }
  }
}

// ---------------------------------------------------------------------------
// Kernel 2 (attnproj): one block per (b, 16-query chunk). 8 waves = 8 heads.
// Phase A: per-wave attention (R6-validated math), V prefetched (issue-early)
//          before softmax; O -> swizzled LDS Osh.
// x residual rows issue-early loaded before Phase B (hide HBM under MFMA).
// Phase B: proj O@Wo + bo, Sp reduce overlapped into the (dead) P region,
//          8x broadcast residual + y store.
// LDS: P 64K (8 KB/wave, reused as Sp in Phase B) | Osh 16K = 80 KB.
// ---------------------------------------------------------------------------
__global__ __launch_bounds__(512) void attnproj(
    const float* __restrict__ x,
    const unsigned short* __restrict__ kbf,
    const unsigned short* __restrict__ vtbf,
    const unsigned short* __restrict__ WoT, const float* __restrict__ bo,
    float* __restrict__ y) {
  __shared__ __align__(16) char lds[65536 + 16384];
  char* Osh = lds + 65536;
  float* Sp = (float*)lds;                    // [8][16][68] overlaps P region
  const int t = threadIdx.x;
  const int lane = t & 63, wid = t >> 6;
  const int c = lane & 15, g = lane >> 4;
  const int bid = blockIdx.x;                 // b*32 + qc
  const int qc = bid & 31, b = bid >> 5;
  const int hh = wid;
  const int qbase = qc * 16;
  char* Pb = lds + wid * 8192;

  // ---------------- Phase A: 16-query attention, head = wave ----------------
  {
    const float* xs = x + (size_t)b * (HW * CH) + (size_t)hh * (LROWS * CH);
    const unsigned short* Kg = kbf + ((size_t)b * MTOK + hh * 32) * INNER;
    const unsigned short* Vg = vtbf + (size_t)(b * HEADS + hh) * (CH * MTOK);

    // Q fragment (B-operand); scale (1/8)*log2e folded in
    const float qs = 0.125f * 1.44269504089f;
    bf16x8 qfr[2];
#pragma unroll
    for (int ks = 0; ks < 2; ++ks) {
      const float* qp = xs + (size_t)(qbase + c) * CH + 32 * ks + 8 * g;
      float4 f0 = *(const float4*)qp;
      float4 f1 = *(const float4*)(qp + 4);
      uint4 u;
      u.x = f2bf(f0.x * qs) | (f2bf(f0.y * qs) << 16);
      u.y = f2bf(f0.z * qs) | (f2bf(f0.w * qs) << 16);
      u.z = f2bf(f1.x * qs) | (f2bf(f1.y * qs) << 16);
      u.w = f2bf(f1.z * qs) | (f2bf(f1.w * qs) << 16);
      qfr[ks] = __builtin_bit_cast(bf16x8, u);
    }

    // S'^T = K . Q^T : acc[kf]; key' = 16*kf + (4g+r), col q = c
    f32x4 acc[16];
#pragma unroll
    for (int kf = 0; kf < 16; ++kf) acc[kf] = (f32x4)0.f;
#pragma unroll
    for (int kf = 0; kf < 16; ++kf) {
      const unsigned short* kp =
          Kg + (size_t)((kf & 1) * 16 + c) * INNER + (kf >> 1) * 64 + 8 * g;
      bf16x8 a0 = ld_bf8(kp);
      bf16x8 a1 = ld_bf8(kp + 32);
      acc[kf] = __builtin_amdgcn_mfma_f32_16x16x32_bf16(a0, qfr[0], acc[kf], 0, 0, 0);
      acc[kf] = __builtin_amdgcn_mfma_f32_16x16x32_bf16(a1, qfr[1], acc[kf], 0, 0, 0);
    }

    // V issue-early prefetch (first half): hides L2 latency under softmax
    uint4 vpre[4][4];
#pragma unroll
    for (int ks = 0; ks < 4; ++ks)
#pragma unroll
      for (int cf = 0; cf < 4; ++cf)
        vpre[ks][cf] =
            *(const uint4*)(Vg + (size_t)(16 * cf + c) * MTOK + 32 * ks + 8 * g);

    // softmax in log2 domain (normalization deferred) + P write
    float m = acc[0][0];
#pragma unroll
    for (int kf = 0; kf < 16; ++kf)
      m = fmaxf(m, fmaxf(fmaxf(acc[kf][0], acc[kf][1]),
                         fmaxf(acc[kf][2], acc[kf][3])));
    m = fmaxf(m, __shfl_xor(m, 16));
    m = fmaxf(m, __shfl_xor(m, 32));
    float sum = 0.f;
    const int rowb = c * 512;               // 256 ushort per P row
#pragma unroll
    for (int kf = 0; kf < 16; ++kf) {
      float e0 = exp2f(acc[kf][0] - m);
      float e1 = exp2f(acc[kf][1] - m);
      float e2 = exp2f(acc[kf][2] - m);
      float e3 = exp2f(acc[kf][3] - m);
      sum += (e0 + e1) + (e2 + e3);
      uint2 w;
      w.x = f2bf(e0) | (f2bf(e1) << 16);
      w.y = f2bf(e2) | (f2bf(e3) << 16);
      *(uint2*)(Pb + ((rowb + (16 * kf + 4 * g) * 2) ^ ((c & 7) << 4))) = w;
    }
    sum += __shfl_xor(sum, 16);
    sum += __shfl_xor(sum, 32);
    const float inv = 1.f / sum;
    asm volatile("" ::: "memory");  // keep P writes before P reads

    // O^T = V^T . P : o[cf], rows=channels, cols=queries
    f32x4 o[4];
#pragma unroll
    for (int cf = 0; cf < 4; ++cf) o[cf] = (f32x4)0.f;
#pragma unroll
    for (int ks = 0; ks < 8; ++ks) {
      bf16x8 p = __builtin_bit_cast(bf16x8,
          *(const uint4*)(Pb + ((c * 512 + (32 * ks + 8 * g) * 2) ^ ((c & 7) << 4))));
#pragma unroll
      for (int cf = 0; cf < 4; ++cf) {
        bf16x8 a = (ks < 4)
            ? __builtin_bit_cast(bf16x8, vpre[ks][cf])
            : ld_bf8(Vg + (size_t)(16 * cf + c) * MTOK + 32 * ks + 8 * g);
        o[cf] = __builtin_amdgcn_mfma_f32_16x16x32_bf16(a, p, o[cf], 0, 0, 0);
      }
    }

    // normalize + store bf16 to Osh[q=c][col = hh*64 + 16cf + 4g + r]
#pragma unroll
    for (int cf = 0; cf < 4; ++cf) {
      f32x4 r = o[cf] * inv;
      uint2 w;
      w.x = f2bf(r[0]) | (f2bf(r[1]) << 16);
      w.y = f2bf(r[2]) | (f2bf(r[3]) << 16);
      int off = (c * 1024 + (hh * 64 + 16 * cf + 4 * g) * 2) ^ ((c & 7) << 4);
      *(uint2*)(Osh + off) = w;
    }
  }

  // x residual rows: issue-early (HBM latency hides under Phase B MFMA)
  const int ei = t >> 5, ejj = t & 31;
  const int ej0 = (ejj & 15) * 4, erh = ejj >> 4;
  const int eL = qbase + ei;
  const float* xr = x + (size_t)b * (HW * CH) + (size_t)eL * 8 * CH + ej0;
  float4 xv[4];
#pragma unroll
  for (int r = 0; r < 4; ++r) xv[r] = *(const float4*)(xr + (erh * 4 + r) * CH);

  __syncthreads();   // P dead from here; its region becomes Sp

  // ---------------- Phase B: proj + residual ----------------
  {
    const int kw = wid * 64;
    f32x4 acc[4];
#pragma unroll
    for (int nt = 0; nt < 4; ++nt) acc[nt] = (f32x4)0.f;
#pragma unroll
    for (int s = 0; s < 2; ++s) {
      const int k0 = kw + s * 32;
      bf16x8 bfr = __builtin_bit_cast(bf16x8,
          *(const uint4*)(Osh + ((c * 1024 + (k0 + 8 * g) * 2) ^ ((c & 7) << 4))));
#pragma unroll
      for (int nt = 0; nt < 4; ++nt) {
        bf16x8 afr = ld_bf8(WoT + (size_t)(nt * 16 + c) * INNER + k0 + 8 * g);
        acc[nt] = __builtin_amdgcn_mfma_f32_16x16x32_bf16(afr, bfr, acc[nt], 0, 0, 0);
      }
    }
#pragma unroll
    for (int nt = 0; nt < 4; ++nt)
      *(f32x4*)&Sp[(wid * 16 + c) * 68 + nt * 16 + 4 * g] = acc[nt];
  }
  __syncthreads();

  // epilogue over all 512 threads
  float4 b4 = *(const float4*)(bo + ej0);
  float4 o4 = b4;
#pragma unroll
  for (int w = 0; w < 8; ++w) {
    float4 s = *(const float4*)&Sp[(w * 16 + ei) * 68 + ej0];
    o4.x += s.x; o4.y += s.y; o4.z += s.z; o4.w += s.w;
  }
  float* yr = y + (size_t)b * (HW * CH) + (size_t)eL * 8 * CH + ej0;
#pragma unroll
  for (int r = 0; r < 4; ++r) {
    float4 ov = make_float4(o4.x + xv[r].x, o4.y + xv[r].y,
                            o4.z + xv[r].z, o4.w + xv[r].w);
    *(float4*)(yr + (erh * 4 + r) * CH) = ov;
  }
}

extern "C" void kernel_launch(void* const* d_in, const int* in_sizes, int n_in,
                              void* d_out, int out_size, void* d_ws, size_t ws_size,
                              hipStream_t stream) {
  const float* x  = (const float*)d_in[0];
  const float* z  = (const float*)d_in[1];
  const float* Wk = (const float*)d_in[2];
  const float* bk = (const float*)d_in[3];
  const float* Wv = (const float*)d_in[4];
  const float* bv = (const float*)d_in[5];
  const float* Wo = (const float*)d_in[6];
  const float* bo = (const float*)d_in[7];
  float* y = (float*)d_out;

  // ws (ushort units): klin 1M | vt 1M | WoT 32K  (~4.3 MB)
  unsigned short* klin = (unsigned short*)d_ws;
  unsigned short* vt   = klin + (size_t)2048 * INNER;
  unsigned short* WoT  = vt   + (size_t)2048 * INNER;

  kv_gen<<<dim3(32, 17), 256, 0, stream>>>(z, Wk, bk, Wv, bv, Wo, klin, vt, WoT);
  attnproj<<<256, 512, 0, stream>>>(x, klin, vt, WoT, bo, y);
}